// Round 12
// baseline (57.329 us; speedup 1.0000x reference)
//
#include <hip/hip_runtime.h>

// BBoxTransform — ONE-PASS concat-space kernel, fp16 LDS corners.
//
// pred_boxes.flat[f] = concat_row[r][c], r=f/N, c=f%N; rows 0..63:
// k=r/8 in {x1,x2=x1,x3=x4,x4,y1,y2=y4,y3=y1,y4}, b=r%8; rows>=64: 1.0.
// An output o's 12 window entries are CONSECUTIVE elements of one concat
// row => one corner type v(k) over columns cs..cs+11.
//
// R11 post-mortem: one-pass at 52.7us was self-limited (occ 14%: 62KB LDS
// = 2 blk/CU; 1.5M LDS conflicts: 48B/lane read stride = 4-way). This
// round: fp16 corners -> 31KB LDS (5 blk/CU), 24B/lane reads (2-way =
// free), 3x ds_read_b64 per window. Target: kernel runs inside the ~39us
// external drain window.

typedef float    f4v __attribute__((ext_vector_type(4)));
typedef float    f4u __attribute__((ext_vector_type(4), aligned(4)));
typedef _Float16 h4  __attribute__((ext_vector_type(4)));

#define S_TILE 3840      // multiple of 12 -> off = cs-cA is a multiple of 12
#define HALO   12
#define ONES_PER_BLK 1024

__device__ __forceinline__ void ones_out(float pcx, float pcy, float ca, float sa,
                                         float* __restrict__ op)
{
    float u0 = 1.0f - pcx, u1 = 1.0f - pcy;
    float v0 = ca * u0 - sa * u1;
    float v1 = sa * u0 + ca * u1;
    float r0 = v0 + pcx, r1 = v1 + pcy;
    f4v val = (f4v){r0, r1, r0, r1};
    ((f4v*)op)[0] = val;
    ((f4v*)op)[1] = val;
}

// fallback concat entry, fp16-rounded to match the LDS path
__device__ __forceinline__ float fb_entry(const float* __restrict__ boxes,
                                          const float* __restrict__ deltas,
                                          int N, int ff)
{
    int rt = ff / N, ct = ff - rt * N;
    if (rt >= 64) return 1.0f;
    int k = rt >> 3, b = rt & 7;
    size_t base = ((size_t)b * N + ct) * 5;
    int comp = (k < 4) ? 0 : 1;
    float b0 = boxes[base + comp], b2 = boxes[base + comp + 2];
    float d0 = deltas[base + comp], d2 = deltas[base + comp + 2];
    float w  = b2 - b0;
    float pc = b0 + 0.5f * w + (d0 * 0.1f) * w;
    float pw = __expf(d2 * 0.2f) * w;
    float v  = ((0xAC >> k) & 1) ? (pc + 0.5f * pw) : (pc - 0.5f * pw);
    return (float)(_Float16)v;
}

__device__ __forceinline__ void emit12(const float* __restrict__ P,
                                       float pcx, float pcy, float ca, float sa,
                                       float* __restrict__ op)
{
    float r0o[4], r1o[4];
#pragma unroll
    for (int j = 0; j < 4; ++j) {
        float p0 = P[j], p1 = P[4 + j], p2 = P[8 + j];
        float u0 = p0 - pcx * p2;          // Tinv @ P
        float u1 = p1 - pcy * p2;
        float v0 = ca * u0 - sa * u1;      // R @ ...
        float v1 = sa * u0 + ca * u1;
        r0o[j] = v0 + pcx * p2;            // T @ ...
        r1o[j] = v1 + pcy * p2;
    }
    ((f4v*)op)[0] = (f4v){r0o[0], r1o[0], r0o[1], r1o[1]};
    ((f4v*)op)[1] = (f4v){r0o[2], r1o[2], r0o[3], r1o[3]};
}

__global__ __launch_bounds__(256) void bbox_onepass(
    const float* __restrict__ boxes, const float* __restrict__ deltas,
    float* __restrict__ out, int N, int total, int iOnes, int nbStage)
{
    __shared__ _Float16 cor[4][S_TILE + HALO];   // 30.8 KB
    int blk = blockIdx.x;

    if (blk < nbStage) {
        int b    = blk & 7;
        int tile = blk >> 3;
        int cA   = tile * S_TILE;
        if (cA >= N) return;
        int cnt  = N - cA; if (cnt > S_TILE + HALO) cnt = S_TILE + HALO;
        int cB   = cA + S_TILE; if (cB > N) cB = N;

        const float* bxBase = boxes  + ((size_t)b * N + cA) * 5;
        const float* dlBase = deltas + ((size_t)b * N + cA) * 5;

        // ---- stage: fp16 corners for columns [cA, cA+cnt) ----
        int quads = (cnt + 3) >> 2;
        for (int q = threadIdx.x; q < quads; q += 256) {
            int j0 = q << 2;
            if (j0 + 4 <= cnt) {
                const f4v* bp = (const f4v*)(bxBase + (size_t)j0 * 5);
                const f4v* dp = (const f4v*)(dlBase + (size_t)j0 * 5);
                float bv[20], dv[20];
                *(f4v*)&bv[0]  = bp[0]; *(f4v*)&bv[4]  = bp[1]; *(f4v*)&bv[8]  = bp[2];
                *(f4v*)&bv[12] = bp[3]; *(f4v*)&bv[16] = bp[4];
                *(f4v*)&dv[0]  = dp[0]; *(f4v*)&dv[4]  = dp[1]; *(f4v*)&dv[8]  = dp[2];
                *(f4v*)&dv[12] = dp[3]; *(f4v*)&dv[16] = dp[4];
                float X1[4], X4[4], Y1[4], Y4[4];
#pragma unroll
                for (int jj = 0; jj < 4; ++jj) {
                    float b0 = bv[jj*5+0], b1 = bv[jj*5+1], b2 = bv[jj*5+2], b3 = bv[jj*5+3];
                    float d0 = dv[jj*5+0], d1 = dv[jj*5+1], d2 = dv[jj*5+2], d3 = dv[jj*5+3];
                    float w  = b2 - b0, h = b3 - b1;
                    float pcx = b0 + 0.5f * w + (d0 * 0.1f) * w;
                    float pcy = b1 + 0.5f * h + (d1 * 0.1f) * h;
                    float pw  = __expf(d2 * 0.2f) * w;
                    float ph  = __expf(d3 * 0.2f) * h;
                    X1[jj] = pcx - 0.5f * pw;  X4[jj] = pcx + 0.5f * pw;
                    Y1[jj] = pcy - 0.5f * ph;  Y4[jj] = pcy + 0.5f * ph;
                }
                *(h4*)&cor[0][j0] = (h4){(_Float16)X1[0],(_Float16)X1[1],(_Float16)X1[2],(_Float16)X1[3]};
                *(h4*)&cor[1][j0] = (h4){(_Float16)X4[0],(_Float16)X4[1],(_Float16)X4[2],(_Float16)X4[3]};
                *(h4*)&cor[2][j0] = (h4){(_Float16)Y1[0],(_Float16)Y1[1],(_Float16)Y1[2],(_Float16)Y1[3]};
                *(h4*)&cor[3][j0] = (h4){(_Float16)Y4[0],(_Float16)Y4[1],(_Float16)Y4[2],(_Float16)Y4[3]};
            } else {
                for (int j = j0; j < cnt; ++j) {
                    const float* bx = bxBase + (size_t)j * 5;
                    const float* dl = dlBase + (size_t)j * 5;
                    float b0 = bx[0], b1 = bx[1], b2 = bx[2], b3 = bx[3];
                    float d0 = dl[0], d1 = dl[1], d2 = dl[2], d3 = dl[3];
                    float w  = b2 - b0, h = b3 - b1;
                    float pcx = b0 + 0.5f * w + (d0 * 0.1f) * w;
                    float pcy = b1 + 0.5f * h + (d1 * 0.1f) * h;
                    float pw  = __expf(d2 * 0.2f) * w;
                    float ph  = __expf(d3 * 0.2f) * h;
                    cor[0][j] = (_Float16)(pcx - 0.5f * pw);
                    cor[1][j] = (_Float16)(pcx + 0.5f * pw);
                    cor[2][j] = (_Float16)(pcy - 0.5f * ph);
                    cor[3][j] = (_Float16)(pcy + 0.5f * ph);
                }
            }
        }
        __syncthreads();

        // ---- emit outputs for the 8 rows r = 8k + b ----
        const int vmap[8] = {0, 0, 1, 1, 2, 3, 2, 3};
#pragma unroll 1
        for (int k = 0; k < 8; ++k) {
            int r = (k << 3) + b;
            long fr = (long)r * N;
            int oFirst = (int)((fr + cA + 11) / 12);
            int oLast  = (int)((fr + cB + 11) / 12) - 1;
            int v = vmap[k];
#pragma unroll 1
            for (int o = oFirst + (int)threadIdx.x; o <= oLast; o += 256) {
                // own record (L3-hot AoS loads)
                const f4u* rb = (const f4u*)(boxes  + (size_t)o * 5);
                const f4u* rd = (const f4u*)(deltas + (size_t)o * 5);
                f4u B0 = rb[0];
                f4u D0 = rd[0];
                float b4 = boxes [(size_t)o * 5 + 4];
                float d4 = deltas[(size_t)o * 5 + 4];
                float w  = B0[2] - B0[0], h = B0[3] - B0[1];
                float pcx = B0[0] + 0.5f * w + (D0[0] * 0.1f) * w;
                float pcy = B0[1] + 0.5f * h + (D0[1] * 0.1f) * h;
                float pal = atanf(d4) + b4;
                float sa = __sinf(pal), ca = __cosf(pal);

                int cs = (int)((long)o * 12 - fr);   // window start col (mult of 12 rel. cA)
                float P[12];
                if (cs + 11 < cA + cnt) {
                    int off = cs - cA;               // multiple of 12 -> 8B-aligned fp16
                    const h4* hp = (const h4*)&cor[v][off];
                    h4 a = hp[0], bb = hp[1], cc = hp[2];
#pragma unroll
                    for (int j = 0; j < 4; ++j) {
                        P[j]     = (float)a[j];
                        P[4 + j] = (float)bb[j];
                        P[8 + j] = (float)cc[j];
                    }
                } else {                             // row-straddler (rare)
#pragma unroll
                    for (int j = 0; j < 12; ++j)
                        P[j] = fb_entry(boxes, deltas, N, o * 12 + j);
                }
                emit12(P, pcx, pcy, ca, sa, out + (size_t)o * 8);
            }
        }
        return;
    }

    // ---- ones tail: outputs o >= iOnes depend only on own box ----
    int i0 = iOnes + (blk - nbStage) * ONES_PER_BLK + (int)threadIdx.x * 4;
#pragma unroll 1
    for (int j = 0; j < 4; ++j) {
        int o = i0 + j;
        if (o >= total) break;
        const f4u* rb = (const f4u*)(boxes  + (size_t)o * 5);
        const f4u* rd = (const f4u*)(deltas + (size_t)o * 5);
        f4u B0 = rb[0];
        f4u D0 = rd[0];
        float b4 = boxes [(size_t)o * 5 + 4];
        float d4 = deltas[(size_t)o * 5 + 4];
        float w  = B0[2] - B0[0], h = B0[3] - B0[1];
        float pcx = B0[0] + 0.5f * w + (D0[0] * 0.1f) * w;
        float pcy = B0[1] + 0.5f * h + (D0[1] * 0.1f) * h;
        float pal = atanf(d4) + b4;
        ones_out(pcx, pcy, __cosf(pal), __sinf(pal), out + (size_t)o * 8);
    }
}

// ---- generic fallback (odd shapes) ----
__global__ __launch_bounds__(256) void bbox_fused_fallback(
    const float* __restrict__ boxes, const float* __restrict__ deltas,
    float* __restrict__ out, int N, int total)
{
    int idx = blockIdx.x * blockDim.x + threadIdx.x;
    if (idx >= total) return;
    int bp = idx / N;
    int n  = idx - bp * N;
    const float* bx = boxes  + (size_t)idx * 5;
    const float* dl = deltas + (size_t)idx * 5;
    float b0=bx[0],b1=bx[1],b2=bx[2],b3=bx[3],b4=bx[4];
    float d0=dl[0],d1=dl[1],d4=dl[4];
    float w=b2-b0, h=b3-b1;
    float pcx = b0+0.5f*w+(d0*0.1f)*w;
    float pcy = b1+0.5f*h+(d1*0.1f)*h;
    float pal = atanf(d4)+b4;
    float sa = __sinf(pal), ca = __cosf(pal);
    int m0 = n*12, q = m0/N, c0 = m0-q*N, r0 = bp*12+q;
    float P[12];
#pragma unroll
    for (int t = 0; t < 12; ++t) {
        int c = c0+t, r = r0;
        if (c >= N) { c -= N; r += 1; }
        P[t] = (r >= 64) ? 1.0f : fb_entry(boxes, deltas, N, r * N + c);
    }
    float r0o[4], r1o[4];
#pragma unroll
    for (int j = 0; j < 4; ++j) {
        float p0=P[j], p1=P[4+j], p2=P[8+j];
        float u0=p0-pcx*p2, u1=p1-pcy*p2;
        float v0=ca*u0-sa*u1, v1=sa*u0+ca*u1;
        r0o[j]=v0+pcx*p2; r1o[j]=v1+pcy*p2;
    }
    float4* op = (float4*)(out + (size_t)idx*8);
    op[0] = make_float4(r0o[0],r1o[0],r0o[1],r1o[1]);
    op[1] = make_float4(r0o[2],r1o[2],r0o[3],r1o[3]);
}

extern "C" void kernel_launch(void* const* d_in, const int* in_sizes, int n_in,
                              void* d_out, int out_size, void* d_ws, size_t ws_size,
                              hipStream_t stream) {
    const float* boxes  = (const float*)d_in[0];
    const float* deltas = (const float*)d_in[1];
    float* out = (float*)d_out;

    int total = in_sizes[0] / 5;     // B * N
    int N = total / 8;               // B == 8
    int threads = 256;

    int iOnes = (int)(((long)64 * N + 11) / 12);
    if (iOnes > total) iOnes = total;

    bool shapeOk = (total == 8 * N) && (N % 4 == 0) && (N >= 24);
    if (shapeOk) {
        int tilesPerBatch = (N + S_TILE - 1) / S_TILE;
        int nbStage = 8 * tilesPerBatch;
        int nOnes   = total - iOnes;
        int nbOnes  = (nOnes + ONES_PER_BLK - 1) / ONES_PER_BLK;
        bbox_onepass<<<nbStage + nbOnes, threads, 0, stream>>>(
            boxes, deltas, out, N, total, iOnes, nbStage);
    } else {
        int blocks = (total + threads - 1) / threads;
        bbox_fused_fallback<<<blocks, threads, 0, stream>>>(boxes, deltas, out, N, total);
    }
}

// Round 13
// 51.686 us; speedup vs baseline: 1.1092x; 1.1092x over previous
//
#include <hip/hip_runtime.h>

// BBoxTransform — two-phase + ones-region absorbed into phase1.
// (Best-known configuration, restored after one-pass variants R11/R12
// measured slower despite fixed occupancy/conflicts.)
//
// pred_boxes.flat[f] = concat_row[r][c], r=f/N, c=f%N; concat rows 0..63:
// k=r/8 in {x1,x2=x1,x3=x4,x4,y1,y2=y4,y3=y1,y4}, batch b=r%8; rows>=64: 1.0.
// V16: 4 distinct corner arrays fp16, v in {0:x1,1:x4,2:y1,3:y4},
// V16[(v*8+b)*N + c]; k->v: k<4 ? k>>1 : 2+(k&1). CTR16[i]=(pcx,pcy,ca,sa).
//
// Final model (R2-R12 evidence): wall = P1 (~39us, pinned by the harness's
// per-replay 256MiB fill dirty-writeback drain — independent of P1's own
// traffic) + P2 (~12us, L3-speed serial tail). Overlap mechanisms refuted:
// grid.sync (R7: 200us), agent-flags (R10: 427us), LDS one-pass (R11/R12:
// 53-57us, double input read + barrier costs exceed the tail).

typedef float    f4v __attribute__((ext_vector_type(4)));
typedef _Float16 h4v __attribute__((ext_vector_type(4)));
typedef _Float16 h8v __attribute__((ext_vector_type(8)));

__device__ __forceinline__ void ones_out(float pcx, float pcy, float ca, float sa,
                                         float* __restrict__ op)
{
    // P == 1 for all 12 entries: same (r0,r1) for all 4 columns.
    float u0 = 1.0f - pcx, u1 = 1.0f - pcy;
    float v0 = ca * u0 - sa * u1;
    float v1 = sa * u0 + ca * u1;
    float r0 = v0 + pcx, r1 = v1 + pcy;
    f4v val = (f4v){r0, r1, r0, r1};
    ((f4v*)op)[0] = val;
    ((f4v*)op)[1] = val;
}

__global__ __launch_bounds__(256) void bbox_phase1(
    const float* __restrict__ boxes, const float* __restrict__ deltas,
    _Float16* __restrict__ V, _Float16* __restrict__ CTR,
    float* __restrict__ out, int N, int total, int iOnes)
{
    int t = blockIdx.x * blockDim.x + threadIdx.x;
    int i0 = t * 4;
    if (i0 >= total) return;

    bool fast = (i0 + 3 < total) && ((N & 3) == 0);
    if (fast) {
        const f4v* bp = (const f4v*)(boxes  + (size_t)i0 * 5);
        const f4v* dp = (const f4v*)(deltas + (size_t)i0 * 5);
        float bv[20], dv[20];
        *(f4v*)&bv[0]  = bp[0]; *(f4v*)&bv[4]  = bp[1]; *(f4v*)&bv[8]  = bp[2];
        *(f4v*)&bv[12] = bp[3]; *(f4v*)&bv[16] = bp[4];
        *(f4v*)&dv[0]  = dp[0]; *(f4v*)&dv[4]  = dp[1]; *(f4v*)&dv[8]  = dp[2];
        *(f4v*)&dv[12] = dp[3]; *(f4v*)&dv[16] = dp[4];

        float X1[4], X4[4], Y1[4], Y4[4], PX[4], PY[4], CA[4], SA[4];
#pragma unroll
        for (int j = 0; j < 4; ++j) {
            float b0 = bv[j*5+0], b1 = bv[j*5+1], b2 = bv[j*5+2],
                  b3 = bv[j*5+3], b4 = bv[j*5+4];
            float d0 = dv[j*5+0], d1 = dv[j*5+1], d2 = dv[j*5+2],
                  d3 = dv[j*5+3], d4 = dv[j*5+4];
            float w  = b2 - b0, h = b3 - b1;
            float pcx = b0 + 0.5f * w + (d0 * 0.1f) * w;
            float pcy = b1 + 0.5f * h + (d1 * 0.1f) * h;
            float pw  = __expf(d2 * 0.2f) * w;
            float ph  = __expf(d3 * 0.2f) * h;
            X1[j] = pcx - 0.5f * pw;  X4[j] = pcx + 0.5f * pw;
            Y1[j] = pcy - 0.5f * ph;  Y4[j] = pcy + 0.5f * ph;
            float pal = atanf(d4) + b4;
            PX[j] = pcx; PY[j] = pcy;
            SA[j] = __sinf(pal); CA[j] = __cosf(pal);
        }
        int b = i0 / N;
        int c = i0 - b * N;
        size_t rs = (size_t)N;
        *(h4v*)(V + (size_t)(0*8 + b) * rs + c) =
            (h4v){(_Float16)X1[0],(_Float16)X1[1],(_Float16)X1[2],(_Float16)X1[3]};
        *(h4v*)(V + (size_t)(1*8 + b) * rs + c) =
            (h4v){(_Float16)X4[0],(_Float16)X4[1],(_Float16)X4[2],(_Float16)X4[3]};
        *(h4v*)(V + (size_t)(2*8 + b) * rs + c) =
            (h4v){(_Float16)Y1[0],(_Float16)Y1[1],(_Float16)Y1[2],(_Float16)Y1[3]};
        *(h4v*)(V + (size_t)(3*8 + b) * rs + c) =
            (h4v){(_Float16)Y4[0],(_Float16)Y4[1],(_Float16)Y4[2],(_Float16)Y4[3]};

        if (i0 + 3 < iOnes) {
            h8v ctrA = {(_Float16)PX[0],(_Float16)PY[0],(_Float16)CA[0],(_Float16)SA[0],
                        (_Float16)PX[1],(_Float16)PY[1],(_Float16)CA[1],(_Float16)SA[1]};
            h8v ctrB = {(_Float16)PX[2],(_Float16)PY[2],(_Float16)CA[2],(_Float16)SA[2],
                        (_Float16)PX[3],(_Float16)PY[3],(_Float16)CA[3],(_Float16)SA[3]};
            *(h8v*)(CTR + (size_t)i0 * 4)     = ctrA;
            *(h8v*)(CTR + (size_t)i0 * 4 + 8) = ctrB;
        } else if (i0 >= iOnes) {
#pragma unroll
            for (int j = 0; j < 4; ++j)
                ones_out(PX[j], PY[j], CA[j], SA[j], out + (size_t)(i0 + j) * 8);
        } else {
#pragma unroll 1
            for (int j = 0; j < 4; ++j) {
                int i = i0 + j;
                if (i < iOnes) {
                    CTR[(size_t)i*4 + 0] = (_Float16)PX[j];
                    CTR[(size_t)i*4 + 1] = (_Float16)PY[j];
                    CTR[(size_t)i*4 + 2] = (_Float16)CA[j];
                    CTR[(size_t)i*4 + 3] = (_Float16)SA[j];
                } else {
                    ones_out(PX[j], PY[j], CA[j], SA[j], out + (size_t)i * 8);
                }
            }
        }
    } else {
#pragma unroll 1
        for (int j = 0; j < 4; ++j) {
            int i = i0 + j;
            if (i >= total) break;
            int bb = i / N, cc = i - bb * N;
            const float* bx = boxes  + (size_t)i * 5;
            const float* dl = deltas + (size_t)i * 5;
            float b0=bx[0],b1=bx[1],b2=bx[2],b3=bx[3],b4=bx[4];
            float d0=dl[0],d1=dl[1],d2=dl[2],d3=dl[3],d4=dl[4];
            float w = b2-b0, h = b3-b1;
            float pcx = b0 + 0.5f*w + (d0*0.1f)*w;
            float pcy = b1 + 0.5f*h + (d1*0.1f)*h;
            float pw = __expf(d2*0.2f)*w, ph = __expf(d3*0.2f)*h;
            size_t rs = (size_t)N;
            V[(size_t)(0*8+bb)*rs + cc] = (_Float16)(pcx - 0.5f*pw);
            V[(size_t)(1*8+bb)*rs + cc] = (_Float16)(pcx + 0.5f*pw);
            V[(size_t)(2*8+bb)*rs + cc] = (_Float16)(pcy - 0.5f*ph);
            V[(size_t)(3*8+bb)*rs + cc] = (_Float16)(pcy + 0.5f*ph);
            float pal = atanf(d4) + b4;
            float ca = __cosf(pal), sa = __sinf(pal);
            if (i < iOnes) {
                CTR[(size_t)i*4 + 0] = (_Float16)pcx;
                CTR[(size_t)i*4 + 1] = (_Float16)pcy;
                CTR[(size_t)i*4 + 2] = (_Float16)ca;
                CTR[(size_t)i*4 + 3] = (_Float16)sa;
            } else {
                ones_out(pcx, pcy, ca, sa, out + (size_t)i * 8);
            }
        }
    }
}

__global__ __launch_bounds__(256) void bbox_phase2(
    const _Float16* __restrict__ V, const _Float16* __restrict__ CTR,
    float* __restrict__ out, int N, int limit)
{
    int t = blockIdx.x * blockDim.x + threadIdx.x;
    int i0 = t * 2;
    if (i0 >= limit) return;

    int f = i0 * 12;
    int r = f / N;
    int c = f - r * N;
    bool pair = (i0 + 1 < limit);

    float P[24];
    bool fast = pair && (c + 23 < N) && ((c & 7) == 0);
    if (fast) {
        if (r < 64) {
            int k = r >> 3, bb = r & 7;
            int v = (k < 4) ? (k >> 1) : (2 + (k & 1));
            const h8v* wp = (const h8v*)(V + (size_t)(v*8 + bb) * N + c);
            h8v a = wp[0], d = wp[1], e = wp[2];
#pragma unroll
            for (int j = 0; j < 8; ++j) {
                P[j]      = (float)a[j];
                P[8 + j]  = (float)d[j];
                P[16 + j] = (float)e[j];
            }
        } else {
#pragma unroll
            for (int j = 0; j < 24; ++j) P[j] = 1.0f;
        }
    } else {
#pragma unroll 1
        for (int j = 0; j < 24; ++j) {
            if (!pair && j >= 12) { P[j] = 1.0f; continue; }
            int ff = f + j;
            int rt = ff / N;
            int ct = ff - rt * N;
            if (rt >= 64) { P[j] = 1.0f; }
            else {
                int k = rt >> 3, bb = rt & 7;
                int v = (k < 4) ? (k >> 1) : (2 + (k & 1));
                P[j] = (float)V[(size_t)(v*8 + bb) * N + ct];
            }
        }
    }

    float pcx[2], pcy[2], cav[2], sav[2];
    if (pair) {
        h8v cc = *(const h8v*)(CTR + (size_t)i0 * 4);
        pcx[0]=(float)cc[0]; pcy[0]=(float)cc[1]; cav[0]=(float)cc[2]; sav[0]=(float)cc[3];
        pcx[1]=(float)cc[4]; pcy[1]=(float)cc[5]; cav[1]=(float)cc[6]; sav[1]=(float)cc[7];
    } else {
        pcx[0]=(float)CTR[(size_t)i0*4+0]; pcy[0]=(float)CTR[(size_t)i0*4+1];
        cav[0]=(float)CTR[(size_t)i0*4+2]; sav[0]=(float)CTR[(size_t)i0*4+3];
        pcx[1]=0.f; pcy[1]=0.f; cav[1]=1.f; sav[1]=0.f;
    }

#pragma unroll
    for (int q = 0; q < 2; ++q) {
        if (q && !pair) break;
        float r0o[4], r1o[4];
#pragma unroll
        for (int j = 0; j < 4; ++j) {
            float p0 = P[q*12 + j], p1 = P[q*12 + 4 + j], p2 = P[q*12 + 8 + j];
            float u0 = p0 - pcx[q] * p2;          // Tinv @ P
            float u1 = p1 - pcy[q] * p2;
            float v0 = cav[q] * u0 - sav[q] * u1; // R @ ...
            float v1 = sav[q] * u0 + cav[q] * u1;
            r0o[j] = v0 + pcx[q] * p2;            // T @ ...
            r1o[j] = v1 + pcy[q] * p2;
        }
        f4v* op = (f4v*)(out + (size_t)(i0 + q) * 8);
        op[0] = (f4v){r0o[0], r1o[0], r0o[1], r1o[1]};
        op[1] = (f4v){r0o[2], r1o[2], r0o[3], r1o[3]};
    }
}

// ---- fused fallback (no workspace) ----
__global__ __launch_bounds__(256) void bbox_fused_fallback(
    const float* __restrict__ boxes, const float* __restrict__ deltas,
    float* __restrict__ out, int N, int total)
{
    int idx = blockIdx.x * blockDim.x + threadIdx.x;
    if (idx >= total) return;
    int bp = idx / N;
    int n  = idx - bp * N;
    const float* bx = boxes  + (size_t)idx * 5;
    const float* dl = deltas + (size_t)idx * 5;
    float b0=bx[0],b1=bx[1],b2=bx[2],b3=bx[3],b4=bx[4];
    float d0=dl[0],d1=dl[1],d4=dl[4];
    float w=b2-b0, h=b3-b1;
    float pcx = b0+0.5f*w+(d0*0.1f)*w;
    float pcy = b1+0.5f*h+(d1*0.1f)*h;
    float pal = atanf(d4)+b4;
    float sa = __sinf(pal), ca = __cosf(pal);
    int m0 = n*12, q = m0/N, c0 = m0-q*N, r0 = bp*12+q;
    float P[12];
#pragma unroll
    for (int t = 0; t < 12; ++t) {
        int c = c0+t, r = r0;
        if (c >= N) { c -= N; r += 1; }
        float v;
        if (r >= 64) v = 1.0f;
        else {
            int k = r>>3, b = r&7;
            size_t base = ((size_t)b*N + c)*5;
            int a = (k<4)?0:1;
            float lo = boxes[base+a], hi = boxes[base+a+2];
            float dc = deltas[base+a], dd = deltas[base+a+2];
            float ww = hi-lo;
            float pc = lo+0.5f*ww+(dc*0.1f)*ww;
            float pwv = __expf(dd*0.2f)*ww;
            float s = ((0xAC>>k)&1)?0.5f:-0.5f;
            v = pc + s*pwv;
        }
        P[t] = v;
    }
    float r0o[4], r1o[4];
#pragma unroll
    for (int j = 0; j < 4; ++j) {
        float p0=P[j], p1=P[4+j], p2=P[8+j];
        float u0=p0-pcx*p2, u1=p1-pcy*p2;
        float v0=ca*u0-sa*u1, v1=sa*u0+ca*u1;
        r0o[j]=v0+pcx*p2; r1o[j]=v1+pcy*p2;
    }
    float4* op = (float4*)(out + (size_t)idx*8);
    op[0] = make_float4(r0o[0],r1o[0],r0o[1],r1o[1]);
    op[1] = make_float4(r0o[2],r1o[2],r0o[3],r1o[3]);
}

extern "C" void kernel_launch(void* const* d_in, const int* in_sizes, int n_in,
                              void* d_out, int out_size, void* d_ws, size_t ws_size,
                              hipStream_t stream) {
    const float* boxes  = (const float*)d_in[0];
    const float* deltas = (const float*)d_in[1];
    float* out = (float*)d_out;

    int total = in_sizes[0] / 5;     // B * N
    int N = total / 8;               // B == 8
    int threads = 256;

    // first idx whose whole 12-wide window is in the ones region (rows >= 64)
    int iOnes = (int)(((long)64 * N + 11) / 12);
    if (iOnes > total) iOnes = total;

    size_t vBytes   = (size_t)32 * N * sizeof(_Float16);
    size_t ctrBytes = (size_t)total * 4 * sizeof(_Float16);
    vBytes = (vBytes + 15) & ~(size_t)15;

    if (ws_size >= vBytes + ctrBytes) {
        _Float16* V   = (_Float16*)d_ws;
        _Float16* CTR = (_Float16*)((char*)d_ws + vBytes);
        int t1 = (total + 3) / 4;
        int blocks1 = (t1 + threads - 1) / threads;
        int t2 = (iOnes + 1) / 2;
        int blocks2 = (t2 + threads - 1) / threads;
        bbox_phase1<<<blocks1, threads, 0, stream>>>(boxes, deltas, V, CTR, out, N, total, iOnes);
        if (blocks2 > 0)
            bbox_phase2<<<blocks2, threads, 0, stream>>>(V, CTR, out, N, iOnes);
    } else {
        int blocks = (total + threads - 1) / threads;
        bbox_fused_fallback<<<blocks, threads, 0, stream>>>(boxes, deltas, out, N, total);
    }
}